// Round 10
// baseline (64.650 us; speedup 1.0000x reference)
//
#include <hip/hip_runtime.h>
#include <hip/hip_bf16.h>

#define TSEQ 256
#define NBATCH 2
#define NAG 8
#define NH 8
#define HD 64
#define EE 512
#define WHALF 16
#define WW 33
#define WN 264   // WW*NAG

typedef __attribute__((ext_vector_type(8))) short short8;
typedef __attribute__((ext_vector_type(4))) short short4v;
typedef __attribute__((ext_vector_type(4))) float f32x4;
typedef _Float16 f16x8 __attribute__((ext_vector_type(8)));

static __device__ __forceinline__ unsigned short f2bf(float f) {
    unsigned int u = __float_as_uint(f);
    unsigned int r = (u + 0x7FFFu + ((u >> 16) & 1u)) >> 16;
    return (unsigned short)r;
}
static __device__ __forceinline__ unsigned short f2h(float f) {
    _Float16 h = (_Float16)f;
    return __builtin_bit_cast(unsigned short, h);
}
static __device__ __forceinline__ float h2f(unsigned short u) {
    return (float)__builtin_bit_cast(_Float16, u);
}
static __device__ __forceinline__ f16x8 as_f16x8(short8 s) {
    return __builtin_bit_cast(f16x8, s);
}

// ---------------- fused QKV projection GEMM (bf16 MFMA) -----------------
// BM=128, BN=128, BK=64, 4 waves (2x2, 64x64 each). z picks {q,k,v}.
// z==2 (v) writes TRANSPOSED vt[b][h][d][key=t*8+m] in **f16** for attn PV.
__global__ __launch_bounds__(256)
void proj_mfma_kernel(const float* __restrict__ xq, const float* __restrict__ xk,
                      const float* __restrict__ xv,
                      const float* __restrict__ Wq, const float* __restrict__ Wk,
                      const float* __restrict__ Wv,
                      const float* __restrict__ bq, const float* __restrict__ bk,
                      const float* __restrict__ bv,
                      unsigned short* __restrict__ oq, unsigned short* __restrict__ ok,
                      unsigned short* __restrict__ vt)
{
    __shared__ char As[128 * 128];   // 128 rows x 64 bf16 (swizzled)
    __shared__ char Bs[128 * 128];

    const float* x; const float* W; const float* bias; float scale;
    const int z = blockIdx.z;
    if (z == 0)      { x = xq; W = Wq; bias = bq; scale = 0.125f; }
    else if (z == 1) { x = xk; W = Wk; bias = bk; scale = 1.0f; }
    else             { x = xv; W = Wv; bias = bv; scale = 1.0f; }

    const int tid  = threadIdx.x;
    const int lane = tid & 63;
    const int wid  = tid >> 6;
    const int i0 = blockIdx.x * 128;
    const int f0 = blockIdx.y * 128;
    const int wr = wid >> 1, wc = wid & 1;

    f32x4 acc[4][4];
    #pragma unroll
    for (int m = 0; m < 4; ++m)
        #pragma unroll
        for (int n = 0; n < 4; ++n)
            acc[m][n] = (f32x4){0.f, 0.f, 0.f, 0.f};

    for (int k0 = 0; k0 < EE; k0 += 64) {
        #pragma unroll
        for (int it = 0; it < 8; ++it) {
            const int tt  = tid + it * 256;        // 0..2047
            const int row = tt >> 4, f4 = tt & 15;
            float4 v4 = *reinterpret_cast<const float4*>(x + (size_t)(i0 + row) * EE + k0 + f4 * 4);
            short4v s;
            s[0] = (short)f2bf(v4.x); s[1] = (short)f2bf(v4.y);
            s[2] = (short)f2bf(v4.z); s[3] = (short)f2bf(v4.w);
            *(short4v*)(As + row * 128 + ((f4 * 8) ^ ((row & 7) << 4))) = s;
        }
        #pragma unroll
        for (int it = 0; it < 8; ++it) {
            const int tt  = tid + it * 256;
            const int row = tt >> 4, f4 = tt & 15;
            float4 v4 = *reinterpret_cast<const float4*>(W + (size_t)(f0 + row) * EE + k0 + f4 * 4);
            short4v s;
            s[0] = (short)f2bf(v4.x); s[1] = (short)f2bf(v4.y);
            s[2] = (short)f2bf(v4.z); s[3] = (short)f2bf(v4.w);
            *(short4v*)(Bs + row * 128 + ((f4 * 8) ^ ((row & 7) << 4))) = s;
        }
        __syncthreads();

        #pragma unroll
        for (int ks = 0; ks < 2; ++ks) {
            short8 a[4], b[4];
            #pragma unroll
            for (int m = 0; m < 4; ++m) {
                const int row = wr * 64 + m * 16 + (lane & 15);
                a[m] = *(short8*)(As + row * 128 +
                                  ((ks * 64 + (lane >> 4) * 16) ^ ((row & 7) << 4)));
            }
            #pragma unroll
            for (int n = 0; n < 4; ++n) {
                const int row = wc * 64 + n * 16 + (lane & 15);
                b[n] = *(short8*)(Bs + row * 128 +
                                  ((ks * 64 + (lane >> 4) * 16) ^ ((row & 7) << 4)));
            }
            #pragma unroll
            for (int m = 0; m < 4; ++m)
                #pragma unroll
                for (int n = 0; n < 4; ++n)
                    acc[m][n] = __builtin_amdgcn_mfma_f32_16x16x32_bf16(a[m], b[n], acc[m][n], 0, 0, 0);
        }
        __syncthreads();
    }

    if (z < 2) {
        unsigned short* o = (z == 0) ? oq : ok;
        #pragma unroll
        for (int n = 0; n < 4; ++n) {
            const int col = f0 + wc * 64 + n * 16 + (lane & 15);
            const float bb = bias[col];
            #pragma unroll
            for (int m = 0; m < 4; ++m)
                #pragma unroll
                for (int rg = 0; rg < 4; ++rg) {
                    const int row = i0 + wr * 64 + m * 16 + (lane >> 4) * 4 + rg;
                    o[(size_t)row * EE + col] = f2bf((acc[m][n][rg] + bb) * scale);
                }
        }
    } else {
        // transposed f16 store: vt[((b*8+h)*64+d)*2048 + (t*8+m)]
        #pragma unroll
        for (int n = 0; n < 4; ++n) {
            const int col = f0 + wc * 64 + n * 16 + (lane & 15);
            const int h = col >> 6, d = col & 63;
            const float bb = bias[col];
            #pragma unroll
            for (int m = 0; m < 4; ++m) {
                const int ibase = i0 + wr * 64 + m * 16 + (lane >> 4) * 4;
                const int bb_ = ibase >> 11;          // batch
                const int key = ibase & 2047;
                ushort4 s4;
                s4.x = f2h(acc[m][n][0] + bb);
                s4.y = f2h(acc[m][n][1] + bb);
                s4.z = f2h(acc[m][n][2] + bb);
                s4.w = f2h(acc[m][n][3] + bb);
                *(ushort4*)(vt + ((size_t)(bb_ * 8 + h) * 64 + d) * 2048 + key) = s4;
            }
        }
    }
}

// ---------------- fused all-heads windowed attention, single-t blocks --------
// Block = (b, t). 512 threads = 8 waves; wave w owns head h = w.
// P in LDS as f16 (logits -> in-place unnormalized probs): 38 KB total ->
// 3-4 blocks/CU. 2 barriers. PV vt prefetch issued before the attn write.
#define RSW  296                        // u16 per P row (592 B, 16B-aligned)
#define HS   2376                       // u16 per head buffer (4752 B, 16B-aligned)
#define KM_OFF_B  (8 * HS * 2)          // 38016
#define INV_OFF_B (KM_OFF_B + 288)      // 38304
#define SMEM2_BYTES (INV_OFF_B + 256 + 32)

__global__ __launch_bounds__(512, 6)
void attn_fused_kernel(const unsigned short* __restrict__ qb,
                       const unsigned short* __restrict__ kb,
                       const unsigned short* __restrict__ vt,
                       const unsigned char* __restrict__ kpm,
                       float* __restrict__ out,
                       float* __restrict__ attn)
{
    extern __shared__ char smem[];
    unsigned short* P16 = (unsigned short*)smem;
    char*  km   = smem + KM_OFF_B;
    float* invs = (float*)(smem + INV_OFF_B);

    // XCD swizzle: each XCD (bid%8) owns a contiguous (b,t) range.
    const int bid = blockIdx.x;
    const int lin = (bid & 7) * 64 + (bid >> 3);   // 0..511
    const int b   = lin >> 8;
    const int t   = lin & 255;
    const int j0  = t - WHALF;
    const int key0 = j0 * 8;
    const int tid = threadIdx.x;
    const int lane = tid & 63;
    const int h    = tid >> 6;             // wave id == head

    // ---- key-valid mask (264 local keys) ----
    if (tid < WN) {
        const int j = j0 + (tid >> 3), m = tid & 7;
        km[tid] = (j >= 0 && j < TSEQ && kpm[(b * TSEQ + j) * NAG + m] == 0) ? 1 : 0;
    }
    // ---- zero P cols [272,296) (PV reads up to 288; QK^T writes [0,272)) ----
    for (int i = tid; i < 768; i += 512) {
        const int row = i / 12, cp = i - row * 12;
        *(unsigned int*)(smem + ((row >> 3) * HS + (row & 7) * RSW + 272 + cp * 2) * 2) = 0u;
    }

    // ---- QK^T per wave: D[8 real rows x 272 cols], depth-5 ring prefetch ----
    {
        const int n = lane & 7;                       // A rows 8..15 duplicate 0..7
        const unsigned short* qbase = qb + ((size_t)(b * TSEQ + t) * NAG + n) * EE + h * HD;
        short8 aq0 = *(const short8*)(qbase + (lane >> 4) * 8);
        short8 aq1 = *(const short8*)(qbase + 32 + (lane >> 4) * 8);
        unsigned short* Ph = P16 + h * HS;
        const int r0 = (lane >> 4) * 4;
        const int cl = lane & 15;

        auto kaddr = [&](int f) -> const unsigned short* {
            const int c = f * 16 + cl;
            int j = j0 + (c >> 3);
            j = (j < 0) ? 0 : ((j > TSEQ - 1) ? TSEQ - 1 : j);
            return kb + ((size_t)(b * TSEQ + j) * NAG + (c & 7)) * EE + h * HD + (lane >> 4) * 8;
        };

        short8 ka[5], kb2[5];
        #pragma unroll
        for (int f = 0; f < 5; ++f) {
            const unsigned short* p = kaddr(f);
            ka[f]  = *(const short8*)p;
            kb2[f] = *(const short8*)(p + 32);
        }
        #pragma unroll
        for (int f = 0; f < 17; ++f) {
            f32x4 a = (f32x4){0.f, 0.f, 0.f, 0.f};
            a = __builtin_amdgcn_mfma_f32_16x16x32_bf16(aq0, ka[f % 5],  a, 0, 0, 0);
            a = __builtin_amdgcn_mfma_f32_16x16x32_bf16(aq1, kb2[f % 5], a, 0, 0, 0);
            if (f + 5 < 17) {
                const unsigned short* p = kaddr(f + 5);
                ka[f % 5]  = *(const short8*)p;
                kb2[f % 5] = *(const short8*)(p + 32);
            }
            if (r0 < 8) {                              // f16 logit write
                #pragma unroll
                for (int rg = 0; rg < 4; ++rg)
                    Ph[(r0 + rg) * RSW + f * 16 + cl] = f2h(a[rg]);
            }
        }
    }
    __syncthreads();

    // ---- softmax per wave: 8 lanes/row; in-place f16 logits -> unnorm probs ----
    {
        const int r = lane & 7, sub = lane >> 3;
        unsigned short* prow = P16 + h * HS + r * RSW;
        float mx = -INFINITY;
        #pragma unroll
        for (int i = 0; i < 33; ++i) {
            const int c = sub + 8 * i;                 // < 264
            if (km[c]) mx = fmaxf(mx, h2f(prow[c]));
        }
        mx = fmaxf(mx, __shfl_xor(mx, 8));
        mx = fmaxf(mx, __shfl_xor(mx, 16));
        mx = fmaxf(mx, __shfl_xor(mx, 32));
        float sum = 0.f;
        #pragma unroll
        for (int i = 0; i < 34; ++i) {
            const int c = sub + 8 * i;                 // covers [0,272)
            float p = 0.f;
            if (c < WN && km[c]) p = __expf(h2f(prow[c]) - mx);
            prow[c] = f2h(p);
            sum += p;
        }
        sum += __shfl_xor(sum, 8);
        sum += __shfl_xor(sum, 16);
        sum += __shfl_xor(sum, 32);
        const float invv = 1.f / sum;
        if (sub == 0) invs[h * 8 + r] = invv;
    }
    __syncthreads();

    // ---- PV vt prefetch issued EARLY (latency hidden under attn write) ----
    const unsigned short* vth = vt + ((size_t)(b * 8 + h) * 64) * 2048;
    auto vaddr = [&](int ms, int df) -> const short8* {
        int kc = key0 + ms * 32 + (lane >> 4) * 8;
        kc = (kc < 0) ? 0 : ((kc > 2040) ? 2040 : kc);
        const int d = df * 16 + (lane & 15);
        return (const short8*)(vth + (size_t)d * 2048 + kc);
    };
    short8 vf[2][4];
    #pragma unroll
    for (int df = 0; df < 4; ++df) vf[0][df] = *vaddr(0, df);
    #pragma unroll
    for (int df = 0; df < 4; ++df) vf[1][df] = *vaddr(1, df);
    __builtin_amdgcn_sched_barrier(0);   // keep prefetch issued before store loop

    // ---- cooperative coalesced attn write: 4224 float4 contiguous ----
    {
        float* abase = attn + (size_t)(b * TSEQ + t) * (NAG * WN * NH);
        #pragma unroll 3
        for (int q4 = tid; q4 < 4224; q4 += 512) {
            const int hh = q4 & 1;
            const int rw = q4 >> 1;                    // n*264 + wm
            const int n  = rw / WN;
            const int wm = rw - n * WN;
            const int h0 = hh * 4;
            const unsigned short* pp = P16 + h0 * HS + n * RSW + wm;
            float4 v;
            v.x = h2f(pp[0])      * invs[(h0 + 0) * 8 + n];
            v.y = h2f(pp[HS])     * invs[(h0 + 1) * 8 + n];
            v.z = h2f(pp[2 * HS]) * invs[(h0 + 2) * 8 + n];
            v.w = h2f(pp[3 * HS]) * invs[(h0 + 3) * 8 + n];
            *(float4*)(abase + (size_t)q4 * 4) = v;
        }
    }
    // no barrier: P16 is read-only from here on

    // ---- PV per wave: D[8 real rows x 64] f16 MFMA; inv applied to acc ----
    {
        const unsigned short* arow = P16 + h * HS + (lane & 7) * RSW;
        f32x4 acc[4];
        #pragma unroll
        for (int df = 0; df < 4; ++df) acc[df] = (f32x4){0.f, 0.f, 0.f, 0.f};

        #pragma unroll
        for (int ms = 0; ms < 9; ++ms) {
            short8 afr = *(const short8*)(arow + ms * 32 + (lane >> 4) * 8);
            #pragma unroll
            for (int df = 0; df < 4; ++df)
                acc[df] = __builtin_amdgcn_mfma_f32_16x16x32_f16(
                    as_f16x8(afr), as_f16x8(vf[ms & 1][df]), acc[df], 0, 0, 0);
            if (ms + 2 < 9) {
                #pragma unroll
                for (int df = 0; df < 4; ++df) vf[ms & 1][df] = *vaddr(ms + 2, df);
            }
        }
        const int r0 = (lane >> 4) * 4;
        if (r0 < 8) {
            float iv[4];
            #pragma unroll
            for (int rg = 0; rg < 4; ++rg) iv[rg] = invs[h * 8 + r0 + rg];
            #pragma unroll
            for (int df = 0; df < 4; ++df) {
                const int d = df * 16 + (lane & 15);
                #pragma unroll
                for (int rg = 0; rg < 4; ++rg) {
                    const int n = r0 + rg;             // row == agent n (single t)
                    out[((size_t)(b * TSEQ + t) * NAG + n) * EE + h * HD + d] = acc[df][rg] * iv[rg];
                }
            }
        }
    }
}

extern "C" void kernel_launch(void* const* d_in, const int* in_sizes, int n_in,
                              void* d_out, int out_size, void* d_ws, size_t ws_size,
                              hipStream_t stream) {
    const float* query = (const float*)d_in[0];
    const float* key   = (const float*)d_in[1];
    const float* value = (const float*)d_in[2];
    const unsigned char* kpm = (const unsigned char*)d_in[3];
    const float* Wq = (const float*)d_in[4];
    const float* bq = (const float*)d_in[5];
    const float* Wk = (const float*)d_in[6];
    const float* bk = (const float*)d_in[7];
    const float* Wv = (const float*)d_in[8];
    const float* bv = (const float*)d_in[9];

    float* out  = (float*)d_out;
    float* attn = out + (size_t)NBATCH * TSEQ * NAG * EE;

    unsigned short* qbf = (unsigned short*)d_ws;               // 4 MB bf16
    unsigned short* kbf = qbf + (size_t)4096 * EE;             // 4 MB bf16
    unsigned short* vtb = kbf + (size_t)4096 * EE;             // 4 MB f16 transposed V

    dim3 gp(32, 4, 3);
    proj_mfma_kernel<<<gp, 256, 0, stream>>>(query, key, value,
                                             Wq, Wk, Wv, bq, bk, bv,
                                             qbf, kbf, vtb);

    (void)hipFuncSetAttribute((const void*)attn_fused_kernel,
                              hipFuncAttributeMaxDynamicSharedMemorySize, SMEM2_BYTES);
    attn_fused_kernel<<<512, 512, SMEM2_BYTES, stream>>>(qbf, kbf, vtb, kpm, out, attn);
}